// Round 15
// baseline (477.203 us; speedup 1.0000x reference)
//
#include <hip/hip_runtime.h>
#include <cfloat>

// Farthest Point Sampling: B=32, N=200000, M=128.
// r14 champion + ONE change: 22 pts in VGPR / 4 pts in LDS (DS reads 3, was 6).
// Topology: 8 blocks/batch x 1024 threads, 1 block/CU (LDS-forced), XCD-local
// batches, LDS atomicMax(u64) intra-block reduce, relaxed u64 tag protocol,
// bounded-backoff MALL poll.
#define B_    32
#define N_    200000
#define M_    128
#define BPB   8                    // blocks per batch
#define T_    1024                 // threads per block
#define PT    26                   // points per thread (13 pairs)
#define NPAIR 13
#define PVP   11                   // pairs in VGPRs (j = 0..21)
#define CHUNK (T_ * PT)            // 26624 points per block; 8*26624 >= N

#define SPIN_CAP (1 << 17)         // hard cap: worst case ~1s total, never a hang

typedef float v2f __attribute__((ext_vector_type(2)));

__global__ __launch_bounds__(T_, 4)
void fps_kernel(const float* __restrict__ pts, int* __restrict__ out,
                unsigned long long* __restrict__ tags) {
#pragma clang fp contract(off)
  const int tid = threadIdx.x;
  const int bid = blockIdx.x;
  // XCD-local batches: blocks round-robin XCDs by bid&7 (measured m09).
  const int xcd = bid & 7;
  const int sl8 = bid >> 3;                  // 0..31 within this XCD
  const int b   = ((sl8 >> 3) << 3) | xcd;   // batch (b&7 == xcd)
  const int c   = sl8 & 7;                   // chunk within batch
  const int wave = tid >> 6;
  const int lane = tid & 63;

  const float* __restrict__ P = pts + (size_t)b * (size_t)(N_ * 3);
  const int base = c * CHUNK + tid;          // this thread's j=0 global index

  // Declared [2] groups (96 KiB) to force 1 block/CU, but only group 0 is
  // used for data (4 points). Thread-private columns, b128 reads, 0 conflicts.
  __shared__ float4 sX[2][T_], sY[2][T_], sZ[2][T_];
  __shared__ unsigned long long sKey[2];     // parity-rotated block argmax key
  __shared__ int    sFar;                    // winner index mailbox

  if (tid == 0) { sKey[0] = 0ull; sKey[1] = 0ull; }

  // ---- one-time load ----
  v2f x2[PVP], y2[PVP], z2[PVP], md2[NPAIR];
  #pragma unroll
  for (int p = 0; p < PVP; ++p) {
    const int g0 = base + (2 * p) * T_, g1 = base + (2 * p + 1) * T_;
    float m0, m1;
    if (g0 < N_) {
      const float* q = P + (size_t)g0 * 3;
      x2[p].x = q[0]; y2[p].x = q[1]; z2[p].x = q[2];
      m0 = __builtin_huge_valf();
    } else { x2[p].x = 0.f; y2[p].x = 0.f; z2[p].x = 0.f; m0 = -FLT_MAX; }
    if (g1 < N_) {
      const float* q = P + (size_t)g1 * 3;
      x2[p].y = q[0]; y2[p].y = q[1]; z2[p].y = q[2];
      m1 = __builtin_huge_valf();
    } else { x2[p].y = 0.f; y2[p].y = 0.f; z2[p].y = 0.f; m1 = -FLT_MAX; }
    md2[p].x = m0; md2[p].y = m1;
  }
  {
    // LDS points: j = 22..25 (pairs 11, 12), group 0 only
    float qx[4], qy[4], qz[4];
    #pragma unroll
    for (int q = 0; q < 4; ++q) {
      const int j = 2 * PVP + q;             // 22..25
      const int gg = base + j * T_;
      float m;
      if (gg < N_) {
        const float* pp = P + (size_t)gg * 3;
        qx[q] = pp[0]; qy[q] = pp[1]; qz[q] = pp[2];
        m = __builtin_huge_valf();
      } else { qx[q] = 0.f; qy[q] = 0.f; qz[q] = 0.f; m = -FLT_MAX; }
      const int pr = PVP + (q >> 1);         // pair index 11..12
      if ((q & 1) == 0) md2[pr].x = m; else md2[pr].y = m;
    }
    sX[0][tid] = make_float4(qx[0], qx[1], qx[2], qx[3]);
    sY[0][tid] = make_float4(qy[0], qy[1], qy[2], qy[3]);
    sZ[0][tid] = make_float4(qz[0], qz[1], qz[2], qz[3]);
    // touch group 1 once so the [2] allocation is retained (forces 1 blk/CU)
    sX[1][tid] = make_float4(0.f, 0.f, 0.f, 0.f);
    sY[1][tid] = make_float4(0.f, 0.f, 0.f, 0.f);
    sZ[1][tid] = make_float4(0.f, 0.f, 0.f, 0.f);
  }
  asm volatile("" ::: "memory");             // keep LDS staging real (r8 bug)
  __syncthreads();

  float cx = P[0], cy = P[1], cz = P[2];     // initial center = point 0
  if (c == 0 && tid == 0) out[b * M_ + 0] = 0;

  for (int it = 1; it < M_; ++it) {
    // ---- packed distance + running-min + 2-parity-chain argmax ----
    // No exclusion select: chosen point's self-distance is exactly 0
    // (coords bit-exact); min(md,0)=0 never beats any positive min-dist.
    // fp contract(off): no fma -> bit-identical to numpy ((dx*dx+dy*dy)+dz*dz).
    const v2f C_x = {cx, cx}, C_y = {cy, cy}, C_z = {cz, cz};
    float bvE = -FLT_MAX, bvO = -FLT_MAX;    // even-j / odd-j chains
    int   bjE = 0x7FFF,   bjO = 0x7FFF;

    #pragma unroll
    for (int p = 0; p < PVP; ++p) {
      v2f dx = x2[p] - C_x;
      v2f dy = y2[p] - C_y;
      v2f dz = z2[p] - C_z;
      v2f s  = (dx * dx + dy * dy) + dz * dz;
      v2f mm = __builtin_elementwise_min(md2[p], s);  // np.minimum
      md2[p] = mm;
      bool tE = mm.x > bvE;                  // ascending j: strict >
      bvE = tE ? mm.x : bvE;
      bjE = tE ? 2 * p : bjE;
      bool tO = mm.y > bvO;
      bvO = tO ? mm.y : bvO;
      bjO = tO ? 2 * p + 1 : bjO;
    }
    {
      float4 qx = sX[0][tid], qy = sY[0][tid], qz = sZ[0][tid];
      #pragma unroll
      for (int h = 0; h < 2; ++h) {          // pairs 11, 12
        const int p = PVP + h;
        v2f X = (h == 0) ? (v2f){qx.x, qx.y} : (v2f){qx.z, qx.w};
        v2f Y = (h == 0) ? (v2f){qy.x, qy.y} : (v2f){qy.z, qy.w};
        v2f Z = (h == 0) ? (v2f){qz.x, qz.y} : (v2f){qz.z, qz.w};
        v2f dx = X - C_x;
        v2f dy = Y - C_y;
        v2f dz = Z - C_z;
        v2f s  = (dx * dx + dy * dy) + dz * dz;
        v2f mm = __builtin_elementwise_min(md2[p], s);
        md2[p] = mm;
        bool tE = mm.x > bvE;
        bvE = tE ? mm.x : bvE;
        bjE = tE ? 2 * p : bjE;
        bool tO = mm.y > bvO;
        bvO = tO ? mm.y : bvO;
        bjO = tO ? 2 * p + 1 : bjO;
      }
    }
    // merge parity chains (tie -> smaller j = smaller global idx)
    bool tk0 = (bvO > bvE) || (bvO == bvE && bjO < bjE);
    float tv = tk0 ? bvO : bvE;
    int   tj = tk0 ? bjO : bjE;
    int   ti = base + tj * T_;               // global idx (< 2^18)

    // ---- wave reduction (64 lanes) ----
    #pragma unroll
    for (int o = 32; o > 0; o >>= 1) {
      float ov = __shfl_xor(tv, o);
      int   oi = __shfl_xor(ti, o);
      bool take = (ov > tv) || (ov == tv && oi < ti);
      tv = take ? ov : tv;
      ti = take ? oi : ti;
    }

    // ---- intra-block reduce: one LDS atomicMax(u64) per wave ----
    // key = (valbits<<32) | (idx ^ 0x3FFFF); tv >= 0 -> bits monotone;
    // inverted idx -> ties pick smaller idx (np first-occurrence).
    if (lane == 0) {
      unsigned long long key =
          ((unsigned long long)__float_as_uint(tv) << 32) |
          (unsigned long long)((unsigned)ti ^ 0x3FFFFu);
      atomicMax(&sKey[it & 1], key);
    }
    if (tid == 0) sKey[(it & 1) ^ 1] = 0ull; // reset other slot pre-barrier
    __syncthreads();                         // barrier #1

    if (wave == 0) {
      unsigned long long* grp = tags + (((b << 1) + (it & 1)) << 3);
      if (lane == 0) {
        unsigned long long k = sKey[it & 1];
        unsigned vbits = (unsigned)(k >> 32);
        unsigned idx   = ((unsigned)k & 0x3FFFFu) ^ 0x3FFFFu;
        unsigned long long tg =
            ((unsigned long long)vbits << 32) |
            ((unsigned long long)idx << 7) | (unsigned)it;
        __hip_atomic_store(grp + c, tg, __ATOMIC_RELAXED, __HIP_MEMORY_SCOPE_AGENT);
      }
      // poll the 8 block tags (lanes 0..7): tight 128 tries, then backoff.
      unsigned long long t = 0;
      if (lane < BPB) {
        int sp = 0;
        for (;;) {
          t = __hip_atomic_load(grp + lane, __ATOMIC_RELAXED, __HIP_MEMORY_SCOPE_AGENT);
          if ((t & 127ull) == (unsigned long long)(unsigned)it) break;
          if (++sp > SPIN_CAP) break;        // wrong answer >> dead container
          if (sp > 128) __builtin_amdgcn_s_sleep(1);
        }
      }
      float cv = (lane < BPB) ? __uint_as_float((unsigned)(t >> 32)) : -FLT_MAX;
      int   ci = (lane < BPB) ? (int)((t >> 7) & 0x3FFFF) : 0x7FFFFFFF;
      #pragma unroll
      for (int o = 4; o > 0; o >>= 1) {
        float ov = __shfl_xor(cv, o);
        int   oi = __shfl_xor(ci, o);
        bool take = (ov > cv) || (ov == cv && oi < ci);
        cv = take ? ov : cv;
        ci = take ? oi : ci;
      }
      if (lane == 0) {
        sFar = ci;                           // index mailbox
        if (c == 0) out[b * M_ + it] = ci;   // fire-and-forget
      }
    }
    __syncthreads();                         // barrier #2

    // all waves fetch winner coords: uniform address -> broadcast load;
    // read-only P (never stale), L1/L2-warm, parallel across waves.
    const int ci = sFar;
    const float* pw = P + (size_t)ci * 3;
    cx = pw[0]; cy = pw[1]; cz = pw[2];
  }
}

extern "C" void kernel_launch(void* const* d_in, const int* in_sizes, int n_in,
                              void* d_out, int out_size, void* d_ws, size_t ws_size,
                              hipStream_t stream) {
  const float*        pts  = (const float*)d_in[0];
  int*                out  = (int*)d_out;
  unsigned long long* tags = (unsigned long long*)d_ws;

  // zero tag slots each launch (tag 0 never matches it>=1); capture-safe
  hipMemsetAsync(d_ws, 0, (size_t)B_ * 2 * BPB * sizeof(unsigned long long), stream);

  // 96 KiB LDS/block -> 1 block/CU; grid == 256 == CU count -> co-resident.
  fps_kernel<<<dim3(B_ * BPB), dim3(T_), 0, stream>>>(pts, out, tags);
}

// Round 16
// 414.320 us; speedup vs baseline: 1.1518x; 1.1518x over previous
//
#include <hip/hip_runtime.h>
#include <cfloat>

// Farthest Point Sampling: B=32, N=200000, M=128.
// r15 topology + value-only hot loop: no per-pair index tracking. Block max
// value via butterfly+LDS atomicMax(u32 bits); index recovered AFTER the
// block max is known by the (rare) matching thread via static re-scan +
// LDS atomicMin(global idx) -> exact np first-occurrence tie-break.
#define B_    32
#define N_    200000
#define M_    128
#define BPB   8                    // blocks per batch
#define T_    1024                 // threads per block
#define PT    26                   // points per thread (13 pairs)
#define NPAIR 13
#define PVP   11                   // pairs in VGPRs (j = 0..21)
#define CHUNK (T_ * PT)            // 26624 points per block; 8*26624 >= N

#define SPIN_CAP (1 << 17)         // hard cap: never hang the container

typedef float v2f __attribute__((ext_vector_type(2)));

__global__ __launch_bounds__(T_, 4)
void fps_kernel(const float* __restrict__ pts, int* __restrict__ out,
                unsigned long long* __restrict__ tags) {
#pragma clang fp contract(off)
  const int tid = threadIdx.x;
  const int bid = blockIdx.x;
  // XCD-local batches: blocks round-robin XCDs by bid&7 (measured m09).
  const int xcd = bid & 7;
  const int sl8 = bid >> 3;                  // 0..31 within this XCD
  const int b   = ((sl8 >> 3) << 3) | xcd;   // batch (b&7 == xcd)
  const int c   = sl8 & 7;                   // chunk within batch
  const int wave = tid >> 6;
  const int lane = tid & 63;

  const float* __restrict__ P = pts + (size_t)b * (size_t)(N_ * 3);
  const int base = c * CHUNK + tid;          // this thread's j=0 global index
                                             // base <= 7*26624+1023 < N: every
                                             // thread's j=0 is VALID -> bv>=0.

  // Declared [2] groups (96 KiB) to force 1 block/CU; only group 0 has data.
  __shared__ float4 sX[2][T_], sY[2][T_], sZ[2][T_];
  __shared__ unsigned sVal[2];               // parity block-max value bits
  __shared__ unsigned sIdx[2];               // parity block argmin index
  __shared__ int      sFar;                  // winner index mailbox

  if (tid == 0) {
    sVal[0] = 0u; sVal[1] = 0u;
    sIdx[0] = 0xFFFFFFFFu; sIdx[1] = 0xFFFFFFFFu;
  }

  // ---- one-time load ----
  v2f x2[PVP], y2[PVP], z2[PVP], md2[NPAIR];
  #pragma unroll
  for (int p = 0; p < PVP; ++p) {
    const int g0 = base + (2 * p) * T_, g1 = base + (2 * p + 1) * T_;
    float m0, m1;
    if (g0 < N_) {
      const float* q = P + (size_t)g0 * 3;
      x2[p].x = q[0]; y2[p].x = q[1]; z2[p].x = q[2];
      m0 = __builtin_huge_valf();
    } else { x2[p].x = 0.f; y2[p].x = 0.f; z2[p].x = 0.f; m0 = -FLT_MAX; }
    if (g1 < N_) {
      const float* q = P + (size_t)g1 * 3;
      x2[p].y = q[0]; y2[p].y = q[1]; z2[p].y = q[2];
      m1 = __builtin_huge_valf();
    } else { x2[p].y = 0.f; y2[p].y = 0.f; z2[p].y = 0.f; m1 = -FLT_MAX; }
    md2[p].x = m0; md2[p].y = m1;
  }
  {
    // LDS points: j = 22..25 (pairs 11, 12), group 0 only
    float qx[4], qy[4], qz[4];
    #pragma unroll
    for (int q = 0; q < 4; ++q) {
      const int j = 2 * PVP + q;             // 22..25
      const int gg = base + j * T_;
      float m;
      if (gg < N_) {
        const float* pp = P + (size_t)gg * 3;
        qx[q] = pp[0]; qy[q] = pp[1]; qz[q] = pp[2];
        m = __builtin_huge_valf();
      } else { qx[q] = 0.f; qy[q] = 0.f; qz[q] = 0.f; m = -FLT_MAX; }
      const int pr = PVP + (q >> 1);         // pair index 11..12
      if ((q & 1) == 0) md2[pr].x = m; else md2[pr].y = m;
    }
    sX[0][tid] = make_float4(qx[0], qx[1], qx[2], qx[3]);
    sY[0][tid] = make_float4(qy[0], qy[1], qy[2], qy[3]);
    sZ[0][tid] = make_float4(qz[0], qz[1], qz[2], qz[3]);
    // touch group 1 so the [2] allocation is retained (forces 1 blk/CU)
    sX[1][tid] = make_float4(0.f, 0.f, 0.f, 0.f);
    sY[1][tid] = make_float4(0.f, 0.f, 0.f, 0.f);
    sZ[1][tid] = make_float4(0.f, 0.f, 0.f, 0.f);
  }
  asm volatile("" ::: "memory");             // keep LDS staging real (r8 bug)
  __syncthreads();

  float cx = P[0], cy = P[1], cz = P[2];     // initial center = point 0
  if (c == 0 && tid == 0) out[b * M_ + 0] = 0;

  for (int it = 1; it < M_; ++it) {
    const int par = it & 1;
    // ---- packed distance + running-min + VALUE-ONLY max ----
    // No exclusion select: self-distance is exactly 0 and never wins.
    // fp contract(off): bit-identical to numpy ((dx*dx+dy*dy)+dz*dz).
    const v2f C_x = {cx, cx}, C_y = {cy, cy}, C_z = {cz, cz};
    float bv = -FLT_MAX;

    #pragma unroll
    for (int p = 0; p < PVP; ++p) {
      v2f dx = x2[p] - C_x;
      v2f dy = y2[p] - C_y;
      v2f dz = z2[p] - C_z;
      v2f s  = (dx * dx + dy * dy) + dz * dz;
      v2f mm = __builtin_elementwise_min(md2[p], s);  // np.minimum
      md2[p] = mm;
      bv = fmaxf(fmaxf(mm.x, mm.y), bv);     // -> v_max3_f32
    }
    {
      float4 qx = sX[0][tid], qy = sY[0][tid], qz = sZ[0][tid];
      #pragma unroll
      for (int h = 0; h < 2; ++h) {          // pairs 11, 12
        const int p = PVP + h;
        v2f X = (h == 0) ? (v2f){qx.x, qx.y} : (v2f){qx.z, qx.w};
        v2f Y = (h == 0) ? (v2f){qy.x, qy.y} : (v2f){qy.z, qy.w};
        v2f Z = (h == 0) ? (v2f){qz.x, qz.y} : (v2f){qz.z, qz.w};
        v2f dx = X - C_x;
        v2f dy = Y - C_y;
        v2f dz = Z - C_z;
        v2f s  = (dx * dx + dy * dy) + dz * dz;
        v2f mm = __builtin_elementwise_min(md2[p], s);
        md2[p] = mm;
        bv = fmaxf(fmaxf(mm.x, mm.y), bv);
      }
    }

    // ---- wave value butterfly (value only, 6 stages) ----
    float wv = bv;
    #pragma unroll
    for (int o = 32; o > 0; o >>= 1)
      wv = fmaxf(wv, __shfl_xor(wv, o));

    // ---- block max value: one LDS atomicMax(u32) per wave ----
    // Every thread's bv >= 0 (j=0 valid) -> float bits are u32-monotone.
    if (lane == 0) atomicMax(&sVal[par], __float_as_uint(wv));
    if (tid == 0) {                          // reset other parity pre-barrier
      sVal[par ^ 1] = 0u;
      sIdx[par ^ 1] = 0xFFFFFFFFu;
    }
    __syncthreads();                         // barrier A: block max final

    // ---- index recovery: only matching thread(s) re-scan (exec-masked) ----
    const unsigned vb = sVal[par];
    if (__float_as_uint(bv) == vb) {         // ~1 thread per block enters
      int jm = 0x7FFFFFFF;
      #pragma unroll
      for (int p = 0; p < NPAIR; ++p) {      // static indexing (rule #20)
        if (jm == 0x7FFFFFFF && __float_as_uint(md2[p].x) == vb) jm = 2 * p;
        if (jm == 0x7FFFFFFF && __float_as_uint(md2[p].y) == vb) jm = 2 * p + 1;
      }
      atomicMin(&sIdx[par], (unsigned)(base + jm * T_));  // smallest glob idx
    }
    __syncthreads();                         // barrier B: block idx final

    if (wave == 0) {
      unsigned long long* grp = tags + (((b << 1) + par) << 3);
      if (lane == 0) {
        // publish block winner: tag = (valbits<<32)|(idx<<7)|iter; RELAXED.
        unsigned long long tg =
            ((unsigned long long)sVal[par] << 32) |
            ((unsigned long long)sIdx[par] << 7) | (unsigned)it;
        __hip_atomic_store(grp + c, tg, __ATOMIC_RELAXED, __HIP_MEMORY_SCOPE_AGENT);
      }
      // poll the 8 block tags (lanes 0..7): tight 128 tries, then backoff.
      unsigned long long t = 0;
      if (lane < BPB) {
        int sp = 0;
        for (;;) {
          t = __hip_atomic_load(grp + lane, __ATOMIC_RELAXED, __HIP_MEMORY_SCOPE_AGENT);
          if ((t & 127ull) == (unsigned long long)(unsigned)it) break;
          if (++sp > SPIN_CAP) break;        // wrong answer >> dead container
          if (sp > 128) __builtin_amdgcn_s_sleep(1);
        }
      }
      float cv = (lane < BPB) ? __uint_as_float((unsigned)(t >> 32)) : -FLT_MAX;
      int   ci = (lane < BPB) ? (int)((t >> 7) & 0x3FFFF) : 0x7FFFFFFF;
      #pragma unroll
      for (int o = 4; o > 0; o >>= 1) {
        float ov = __shfl_xor(cv, o);
        int   oi = __shfl_xor(ci, o);
        bool take = (ov > cv) || (ov == cv && oi < ci);
        cv = take ? ov : cv;
        ci = take ? oi : ci;
      }
      if (lane == 0) {
        sFar = ci;                           // index mailbox
        if (c == 0) out[b * M_ + it] = ci;   // fire-and-forget
      }
    }
    __syncthreads();                         // barrier C

    // all waves fetch winner coords: uniform address -> broadcast load;
    // read-only P (never stale), L2-warm, parallel across waves.
    const int ci = sFar;
    const float* pw = P + (size_t)ci * 3;
    cx = pw[0]; cy = pw[1]; cz = pw[2];
  }
}

extern "C" void kernel_launch(void* const* d_in, const int* in_sizes, int n_in,
                              void* d_out, int out_size, void* d_ws, size_t ws_size,
                              hipStream_t stream) {
  const float*        pts  = (const float*)d_in[0];
  int*                out  = (int*)d_out;
  unsigned long long* tags = (unsigned long long*)d_ws;

  // zero tag slots each launch (tag 0 never matches it>=1); capture-safe
  hipMemsetAsync(d_ws, 0, (size_t)B_ * 2 * BPB * sizeof(unsigned long long), stream);

  // 96 KiB LDS/block -> 1 block/CU; grid == 256 == CU count -> co-resident.
  fps_kernel<<<dim3(B_ * BPB), dim3(T_), 0, stream>>>(pts, out, tags);
}